// Round 10
// baseline (210.847 us; speedup 1.0000x reference)
//
#include <hip/hip_runtime.h>
#include <hip/hip_bf16.h>
#include <cstdint>
#include <cstddef>

// ---------------------------------------------------------------------------
// Fused MHA block: x@Wqkv^T -> RoPE -> causal flash attention -> @Wo^T
// B=2 S=2048 H=16 DK=64. fp32 in/out, bf16 MFMA compute (fp32 accum).
//
// R10: attn rework (GEMM = R9, verified: conflicts 0, 568 TF ~ 2ph ceiling).
//  (a) UNPAIR: 1024 blocks x 4 waves, one q-tile each, longest-first
//      (qt = NT-1-bx). No barrier-idle waves (paired avg util was ~70%).
//      LDS 40KB -> 4 blocks/CU, 16 waves/CU all useful.
//  (b) T2 XOR swizzle on attn K/V/P LDS (port of GEMM's measured-zero
//      pattern): stride 64, write granule g^(row&7), read (ks*4+lg)^(lr&7).
//      P written as b64 halves into swizzled 16B granules.
// Predict: attn ~42 -> 26-32us, attn conflicts 7.6M -> <1M, total -> 112-120.
// ---------------------------------------------------------------------------

typedef unsigned short u16;
typedef unsigned int   u32;

typedef float f32x4 __attribute__((ext_vector_type(4)));
typedef short frag_t __attribute__((ext_vector_type(8)));

__device__ __forceinline__ f32x4 mfma16(frag_t a, frag_t b, f32x4 c) {
  return __builtin_amdgcn_mfma_f32_16x16x32_bf16(a, b, c, 0, 0, 0);
}

typedef __attribute__((address_space(1))) void as1_void;
typedef __attribute__((address_space(3))) void as3_void;
__device__ __forceinline__ void gload_lds16(const void* g, void* l) {
  __builtin_amdgcn_global_load_lds((as1_void*)g, (as3_void*)l, 16, 0, 0);
}

__device__ __forceinline__ u16 f2bf(float f) {  // RNE fp32 -> bf16
  u32 u = __builtin_bit_cast(u32, f);
  u += 0x7fffu + ((u >> 16) & 1u);
  return (u16)(u >> 16);
}
__device__ __forceinline__ float bf2f(u16 h) {
  u32 u = ((u32)h) << 16;
  return __builtin_bit_cast(float, u);
}
__device__ __forceinline__ u16 bf16u(float f) {  // via compiler cvt path
  __hip_bfloat16 h = __float2bfloat16(f);
  u16 u;
  __builtin_memcpy(&u, &h, 2);
  return u;
}
__device__ __forceinline__ float exp2_hw(float x) {  // raw v_exp_f32
  float r;
  asm("v_exp_f32 %0, %1" : "=v"(r) : "v"(x));
  return r;
}

static constexpr int Bb = 2, Ss = 2048, Hh = 16, Dd = 1024;
static constexpr int Mm = Bb * Ss;  // 4096
static constexpr int NT = Ss / 64;  // 32 k/q tiles

// ---------------------------------------------------------------------------
// 0) fp32 -> bf16 convert
// ---------------------------------------------------------------------------
__global__ __launch_bounds__(256) void cvt_f32_bf16(const float* __restrict__ in,
                                                    u16* __restrict__ out, int n4) {
  for (int i = blockIdx.x * blockDim.x + threadIdx.x; i < n4;
       i += gridDim.x * blockDim.x) {
    float4 v = ((const float4*)in)[i];
    ushort4 o;
    o.x = f2bf(v.x); o.y = f2bf(v.y); o.z = f2bf(v.z); o.w = f2bf(v.w);
    ((ushort4*)out)[i] = o;
  }
}

// ---------------------------------------------------------------------------
// 0b) RoPE cos/sin table
// ---------------------------------------------------------------------------
__global__ __launch_bounds__(256) void build_rope_table(float2* __restrict__ tab) {
  int i = blockIdx.x * blockDim.x + threadIdx.x;
  if (i >= Ss * 32) return;
  int s = i >> 5, j = i & 31;
  const float log2_theta_over_32 = 0.41524101186091903f;  // log2(10000)/32
  float inv = exp2f(-(float)j * log2_theta_over_32);
  float fr = (float)s * inv;
  float sn, cs;
  sincosf(fr, &sn, &cs);
  tab[i] = make_float2(cs, sn);
}

// ---------------------------------------------------------------------------
// 1) GEMM C[m,n] = sum_k A[m,k] * B[n,k]
//    128x128 tile, dbuf LDS, T2 swizzle, T4 counted-vmcnt depth-2 pipeline.
//    (R9, verified: SQ_LDS_BANK_CONFLICT = 0)
// ---------------------------------------------------------------------------
template <bool OUT_BF16>
__global__ __launch_bounds__(256) void gemm_bt_kernel(const u16* __restrict__ A,
                                                      const u16* __restrict__ Bm,
                                                      void* __restrict__ Cv,
                                                      int Mdim, int Ndim, int Kdim) {
  __shared__ __align__(16) u16 As[2][128 * 64];
  __shared__ __align__(16) u16 Bs[2][128 * 64];
  const int tid = threadIdx.x;
  const int lane = tid & 63, wid = tid >> 6;
  const int wr = wid >> 1, wc = wid & 1;
  const int lr = lane & 15, lg = lane >> 4;

  // XCD-aware swizzle (T1): nwg % 8 == 0 for both launches (768, 256)
  const int nwg = gridDim.x * gridDim.y;
  const int orig = blockIdx.y * gridDim.x + blockIdx.x;
  const int cpx = nwg >> 3;
  const int swz = (orig & 7) * cpx + (orig >> 3);
  const int bx = swz % gridDim.x, by = swz / gridDim.x;
  const int m0 = by * 128, n0 = bx * 128;

  f32x4 acc[4][4] = {};

  // T2 (rule #21): LDS dest linear; global SOURCE granule pre-swizzled so
  // LDS(row, c) = Global(row, c ^ (row&7)).  row&7 == lane>>3 here.
  const int rowA = lane >> 3;
  const int colu = ((lane & 7) ^ rowA) * 8;  // u16 offset of 16B granule

  auto stage = [&](int buf, int kt) {
#pragma unroll
    for (int i = 0; i < 4; i++) {
      int chunk = wid * 4 + i;  // wave-uniform
      const u16* ga = A + (size_t)(m0 + chunk * 8 + rowA) * Kdim + kt + colu;
      gload_lds16(ga, &As[buf][chunk * 512]);
      const u16* gb = Bm + (size_t)(n0 + chunk * 8 + rowA) * Kdim + kt + colu;
      gload_lds16(gb, &Bs[buf][chunk * 512]);
    }
  };

  const int niter = Kdim >> 6;  // requires Kdim >= 128 (here: 1024)

  // prologue: fill both buffers, wait only for buf0's 8 loads
  stage(0, 0);
  stage(1, 64);
  asm volatile("s_waitcnt vmcnt(8)" ::: "memory");
  __builtin_amdgcn_sched_barrier(0);
  __builtin_amdgcn_s_barrier();
  __builtin_amdgcn_sched_barrier(0);

  const int rsw = (lr & 7) * 8;  // T2 read-side XOR (u16 units)
  int cur = 0;
  for (int it = 0; it < niter; ++it) {
#pragma unroll
    for (int ks = 0; ks < 2; ks++) {
      frag_t a[4], b[4];
#pragma unroll
      for (int mt = 0; mt < 4; mt++)
        a[mt] = *(const frag_t*)&As[cur][(wr * 64 + mt * 16 + lr) * 64 +
                                         ((ks * 32 + lg * 8) ^ rsw)];
#pragma unroll
      for (int nt = 0; nt < 4; nt++)
        b[nt] = *(const frag_t*)&Bs[cur][(wc * 64 + nt * 16 + lr) * 64 +
                                         ((ks * 32 + lg * 8) ^ rsw)];
#pragma unroll
      for (int mt = 0; mt < 4; mt++)
#pragma unroll
        for (int nt = 0; nt < 4; nt++)
          acc[mt][nt] = mfma16(a[mt], b[nt], acc[mt][nt]);
    }

    if (it + 1 < niter) {
      __builtin_amdgcn_s_barrier();      // all waves done reading buf cur
      __builtin_amdgcn_sched_barrier(0);
      if (it + 2 < niter) {
        stage(cur, (it + 2) << 6);       // refill just-read buf; 16 in flight
        asm volatile("s_waitcnt vmcnt(8)" ::: "memory");  // oldest 8 = next buf
      } else {
        asm volatile("s_waitcnt vmcnt(0)" ::: "memory");  // tail drain
      }
      __builtin_amdgcn_sched_barrier(0);
      __builtin_amdgcn_s_barrier();      // cross-wave: next buf visible
      __builtin_amdgcn_sched_barrier(0);
      cur ^= 1;
    }
  }

#pragma unroll
  for (int mt = 0; mt < 4; mt++)
#pragma unroll
    for (int nt = 0; nt < 4; nt++)
#pragma unroll
      for (int r = 0; r < 4; r++) {
        size_t row = (size_t)(m0 + wr * 64 + mt * 16 + lg * 4 + r);
        size_t col = (size_t)(n0 + wc * 64 + nt * 16 + lr);
        if (OUT_BF16)
          ((u16*)Cv)[row * Ndim + col] = f2bf(acc[mt][nt][r]);
        else
          ((float*)Cv)[row * Ndim + col] = acc[mt][nt][r];
      }
}

// ---------------------------------------------------------------------------
// 2) RoPE + reshape. Q pre-scaled by 0.125*log2(e): scores in log2 units.
// ---------------------------------------------------------------------------
__global__ __launch_bounds__(256) void rope_kernel(const u16* __restrict__ qkv,
                                                   const float2* __restrict__ tab,
                                                   u16* __restrict__ q_r,
                                                   u16* __restrict__ k_r,
                                                   u16* __restrict__ vt) {
  const int bh = blockIdx.y, b = bh >> 4, h = bh & 15;
  const int s0 = blockIdx.x * 64;
  const int t = threadIdx.x;
  __shared__ __align__(16) u16 Vls[64 * 72];

  const int srow = t >> 2, c4 = t & 3;
  const int s = s0 + srow;
  const size_t rowbase = (size_t)(b * Ss + s) * 3072 + h * 64 + c4 * 16;

  u16 xq[16] __attribute__((aligned(16)));
  u16 xk[16] __attribute__((aligned(16)));
  u16 xv[16] __attribute__((aligned(16)));
  *(uint4*)&xq[0] = *(const uint4*)(qkv + rowbase);
  *(uint4*)&xq[8] = *(const uint4*)(qkv + rowbase + 8);
  *(uint4*)&xk[0] = *(const uint4*)(qkv + rowbase + 1024);
  *(uint4*)&xk[8] = *(const uint4*)(qkv + rowbase + 1024 + 8);
  *(uint4*)&xv[0] = *(const uint4*)(qkv + rowbase + 2048);
  *(uint4*)&xv[8] = *(const uint4*)(qkv + rowbase + 2048 + 8);

  u16 oq[16] __attribute__((aligned(16)));
  u16 ok[16] __attribute__((aligned(16)));
  const int j0 = c4 * 8;
  const float qscale = 0.125f * 1.4426950408889634f;  // 1/sqrt(64) * log2(e)
#pragma unroll
  for (int p = 0; p < 8; p++) {
    float2 cs = tab[s * 32 + j0 + p];
    float q1 = bf2f(xq[2 * p]), q2 = bf2f(xq[2 * p + 1]);
    float k1 = bf2f(xk[2 * p]), k2 = bf2f(xk[2 * p + 1]);
    oq[2 * p]     = f2bf((q1 * cs.x - q2 * cs.y) * qscale);
    oq[2 * p + 1] = f2bf((q1 * cs.y + q2 * cs.x) * qscale);
    ok[2 * p]     = f2bf(k1 * cs.x - k2 * cs.y);
    ok[2 * p + 1] = f2bf(k1 * cs.y + k2 * cs.x);
  }
  const size_t obase = ((size_t)bh * Ss + s) * 64 + c4 * 16;
  *(uint4*)(q_r + obase)     = *(uint4*)&oq[0];
  *(uint4*)(q_r + obase + 8) = *(uint4*)&oq[8];
  *(uint4*)(k_r + obase)     = *(uint4*)&ok[0];
  *(uint4*)(k_r + obase + 8) = *(uint4*)&ok[8];

  *(uint4*)&Vls[srow * 72 + c4 * 16]     = *(uint4*)&xv[0];
  *(uint4*)&Vls[srow * 72 + c4 * 16 + 8] = *(uint4*)&xv[8];
  __syncthreads();
  const int d = t >> 2, cq = t & 3;
  u16 ov[16] __attribute__((aligned(16)));
#pragma unroll
  for (int i = 0; i < 16; i++) ov[i] = Vls[(cq * 16 + i) * 72 + d];
  const size_t vbase = ((size_t)bh * 64 + d) * Ss + s0 + cq * 16;
  *(uint4*)(vt + vbase)     = *(uint4*)&ov[0];
  *(uint4*)(vt + vbase + 8) = *(uint4*)&ov[8];
}

// ---------------------------------------------------------------------------
// 3) Flash attention (causal). UNPAIRED: 1024 blocks (32 qt x 32 bh), 4 waves
//    each, qt = NT-1-bx (longest first). All waves active every iteration.
//    Swapped QK^T, no max tracking, T2 XOR-swizzled K/V/P LDS (stride 64,
//    granule ^ (row&7) on both write and read -> GEMM-verified 0-conflict
//    pattern). Double-buffered K/V, 1 barrier/iter.
// ---------------------------------------------------------------------------
__global__ __launch_bounds__(256, 4) void attn_kernel(const u16* __restrict__ q_r,
                                                      const u16* __restrict__ k_r,
                                                      const u16* __restrict__ vt,
                                                      u16* __restrict__ o) {
  const int qt = NT - 1 - blockIdx.x;  // longest blocks dispatched first
  const int bh = blockIdx.y;
  const int b = bh >> 4, h = bh & 15;
  const int tid = threadIdx.x;
  const int lane = tid & 63, w = tid >> 6;  // w in 0..3
  const int lr = lane & 15, lg = lane >> 4;

  __shared__ __align__(16) u16 Ks[2][64 * 64];
  __shared__ __align__(16) u16 Vs[2][64 * 64];
  __shared__ __align__(16) u16 Ps[4][16 * 64];

  const size_t kvbase = (size_t)bh * Ss * 64;
  const size_t vtbase = (size_t)bh * 64 * Ss;
  u16* Pw = &Ps[w][0];
  const int qrow = w * 16 + lr;
  const int sw = lr & 7;  // read-side row XOR key

  // ---- Q fragments in registers (once) ----
  frag_t q0f, q1f;
  {
    const u16* qa = q_r + kvbase + (size_t)(qt * 64 + qrow) * 64 + lg * 8;
    q0f = *(const frag_t*)qa;
    q1f = *(const frag_t*)(qa + 32);
  }

  // staging: 256 threads x 2 chunks of the 64x64 tile per tensor.
  // LDS write granule swizzled: g' = g ^ (row&7)  (row&7 same for srow0/srow1)
  const int srow0 = tid >> 3, srow1 = srow0 + 32;
  const int sgr = tid & 7;                       // global 16B granule
  const int scolg = (sgr * 8);                   // global col (u16)
  const int scols = ((sgr ^ (srow0 & 7)) * 8);   // swizzled LDS col (u16)
  uint4 kreg[2], vreg[2];
  const u16* kp = k_r + kvbase;
  const u16* vp = vt + vtbase;

  auto issue = [&](int kt) {
    kreg[0] = *(const uint4*)(kp + (size_t)(kt * 64 + srow0) * 64 + scolg);
    kreg[1] = *(const uint4*)(kp + (size_t)(kt * 64 + srow1) * 64 + scolg);
    vreg[0] = *(const uint4*)(vp + (size_t)srow0 * Ss + kt * 64 + scolg);
    vreg[1] = *(const uint4*)(vp + (size_t)srow1 * Ss + kt * 64 + scolg);
  };
  auto commit = [&](int buf) {
    *(uint4*)&Ks[buf][srow0 * 64 + scols] = kreg[0];
    *(uint4*)&Ks[buf][srow1 * 64 + scols] = kreg[1];
    *(uint4*)&Vs[buf][srow0 * 64 + scols] = vreg[0];
    *(uint4*)&Vs[buf][srow1 * 64 + scols] = vreg[1];
  };

  f32x4 oacc[4] = {};
  float l_run = 0.f;

  issue(0);
  commit(0);
  __syncthreads();

  for (int kt = 0; kt <= qt; kt++) {
    const int cur = kt & 1;
    const bool last = (kt == qt);
    if (!last) issue(kt + 1);  // next tile's loads in flight under compute

    // ---- S^T = K @ Q^T (swizzled K reads: granule (ks*4+lg)^(lr&7)) ----
    f32x4 sa[4];
    __builtin_amdgcn_s_setprio(1);
#pragma unroll
    for (int kf = 0; kf < 4; kf++) {
      frag_t k0 = *(const frag_t*)&Ks[cur][(kf * 16 + lr) * 64 + ((lg ^ sw) * 8)];
      frag_t k1 = *(const frag_t*)&Ks[cur][(kf * 16 + lr) * 64 + (((4 + lg) ^ sw) * 8)];
      sa[kf] = mfma16(k0, q0f, f32x4{0.f, 0.f, 0.f, 0.f});
      sa[kf] = mfma16(k1, q1f, sa[kf]);
    }
    __builtin_amdgcn_s_setprio(0);

    if (last) {  // diagonal mask (uniform branch)
#pragma unroll
      for (int kf = 0; kf < 4; kf++)
#pragma unroll
        for (int r = 0; r < 4; r++)
          if (kf * 16 + lg * 4 + r > qrow) sa[kf][r] = -1e30f;
    }

    // ---- p = exp2(s), lane-local l, pack, write P (swizzled b64) ----
    float ls = 0.f;
#pragma unroll
    for (int kf = 0; kf < 4; kf++) {
      float p0 = exp2_hw(sa[kf][0]), p1 = exp2_hw(sa[kf][1]);
      float p2 = exp2_hw(sa[kf][2]), p3 = exp2_hw(sa[kf][3]);
      ls += (p0 + p1) + (p2 + p3);
      ushort4 w4;
      w4.x = bf16u(p0); w4.y = bf16u(p1); w4.z = bf16u(p2); w4.w = bf16u(p3);
      // k-range [kf*16+lg*4, +4) -> granule kf*2+(lg>>1), half lg&1
      const int pg = (kf * 2 + (lg >> 1)) ^ sw;
      *(ushort4*)&Pw[lr * 64 + pg * 8 + (lg & 1) * 4] = w4;
    }
    l_run += ls;

    // ---- PV from LDS P (swizzled reads) ----
    __builtin_amdgcn_s_setprio(1);
#pragma unroll
    for (int ks = 0; ks < 2; ks++) {
      frag_t pa = *(const frag_t*)&Pw[lr * 64 + (((ks * 4 + lg) ^ sw) * 8)];
#pragma unroll
      for (int df = 0; df < 4; df++) {
        frag_t bv = *(const frag_t*)&Vs[cur][(df * 16 + lr) * 64 +
                                             (((ks * 4 + lg) ^ sw) * 8)];
        oacc[df] = mfma16(pa, bv, oacc[df]);
      }
    }
    __builtin_amdgcn_s_setprio(0);

    if (!last) commit(cur ^ 1);
    __syncthreads();
  }

  // ---- epilogue: reduce l across lg groups, O /= l, write bf16 ----
  l_run += __shfl_xor(l_run, 16);
  l_run += __shfl_xor(l_run, 32);
#pragma unroll
  for (int r = 0; r < 4; r++) {
    float il = 1.0f / __shfl(l_run, lg * 4 + r);
    size_t row = (size_t)b * Ss + qt * 64 + w * 16 + lg * 4 + r;
#pragma unroll
    for (int df = 0; df < 4; df++)
      o[row * 1024 + h * 64 + df * 16 + lr] = f2bf(oacc[df][r] * il);
  }
}

// ---------------------------------------------------------------------------
// launch
// ---------------------------------------------------------------------------
extern "C" void kernel_launch(void* const* d_in, const int* in_sizes, int n_in,
                              void* d_out, int out_size, void* d_ws, size_t ws_size,
                              hipStream_t stream) {
  const float* x    = (const float*)d_in[0];
  const float* Wqkv = (const float*)d_in[1];
  const float* Wo   = (const float*)d_in[2];
  float* out = (float*)d_out;
  char* ws = (char*)d_ws;

  constexpr size_t TAB_OFF  = 0;                       // 512KB
  constexpr size_t XB_OFF   = TAB_OFF + 524288;        // 8MB
  constexpr size_t WQB_OFF  = XB_OFF + 8388608;        // 6MB
  constexpr size_t WOB_OFF  = WQB_OFF + 6291456;       // 2MB
  constexpr size_t QKV_OFF  = WOB_OFF + 2097152;       // 24MB
  constexpr size_t QR_OFF   = QKV_OFF + 25165824;      // 8MB
  constexpr size_t KR_OFF   = QR_OFF + 8388608;        // 8MB
  constexpr size_t VT_OFF   = KR_OFF + 8388608;        // 8MB
  constexpr size_t AO_OFF   = VT_OFF + 8388608;        // 8MB

  float2* tab = (float2*)(ws + TAB_OFF);
  u16* xb     = (u16*)(ws + XB_OFF);
  u16* wqkvb  = (u16*)(ws + WQB_OFF);
  u16* wob    = (u16*)(ws + WOB_OFF);
  u16* qkv    = (u16*)(ws + QKV_OFF);
  u16* q_r    = (u16*)(ws + QR_OFF);
  u16* k_r    = (u16*)(ws + KR_OFF);
  u16* vt     = (u16*)(ws + VT_OFF);
  u16* ao     = (u16*)(ws + AO_OFF);

  build_rope_table<<<256, 256, 0, stream>>>(tab);
  cvt_f32_bf16<<<2048, 256, 0, stream>>>(x, xb, Mm * Dd / 4);
  cvt_f32_bf16<<<1536, 256, 0, stream>>>(Wqkv, wqkvb, 3 * Dd * Dd / 4);
  cvt_f32_bf16<<<512, 256, 0, stream>>>(Wo, wob, Dd * Dd / 4);

  gemm_bt_kernel<true><<<dim3(3 * Dd / 128, Mm / 128), 256, 0, stream>>>(
      xb, wqkvb, qkv, Mm, 3 * Dd, Dd);

  rope_kernel<<<dim3(Ss / 64, Bb * Hh), 256, 0, stream>>>(qkv, tab, q_r, k_r, vt);

  attn_kernel<<<dim3(NT, Bb * Hh), 256, 0, stream>>>(q_r, k_r, vt, ao);

  gemm_bt_kernel<false><<<dim3(Dd / 128, Mm / 128), 256, 0, stream>>>(
      ao, wob, out, Mm, Dd, Dd);
}

// Round 11
// 129.823 us; speedup vs baseline: 1.6241x; 1.6241x over previous
//
#include <hip/hip_runtime.h>
#include <hip/hip_bf16.h>
#include <cstdint>
#include <cstddef>

// ---------------------------------------------------------------------------
// Fused MHA block: x@Wqkv^T -> RoPE -> causal flash attention -> @Wo^T
// B=2 S=2048 H=16 DK=64. fp32 in/out, bf16 MFMA compute (fp32 accum).
//
// R11: recompose from verified parts. R10 regressed (unpairing: 2x staging
// traffic, no backfill, compiler restructure) but VERIFIED the attn swizzle
// math (pass, conflicts 7.6M->1.08M). This round = R7 attn structure (paired
// q-tiles, 8 waves, 42us measured) + that swizzle, nothing else:
//   K/V/P LDS stride 64, write granule g^(row&7), K/V/P reads granule
//   (ks*4+lg)^(lr&7), P write granule (kf*2+(lg>>1))^(lr&7) half lg&1.
// LDS 55.3 -> 48KB. GEMM = R9 (verified conflicts 0). rope/cvt unchanged.
// ---------------------------------------------------------------------------

typedef unsigned short u16;
typedef unsigned int   u32;

typedef float f32x4 __attribute__((ext_vector_type(4)));
typedef short frag_t __attribute__((ext_vector_type(8)));

__device__ __forceinline__ f32x4 mfma16(frag_t a, frag_t b, f32x4 c) {
  return __builtin_amdgcn_mfma_f32_16x16x32_bf16(a, b, c, 0, 0, 0);
}

typedef __attribute__((address_space(1))) void as1_void;
typedef __attribute__((address_space(3))) void as3_void;
__device__ __forceinline__ void gload_lds16(const void* g, void* l) {
  __builtin_amdgcn_global_load_lds((as1_void*)g, (as3_void*)l, 16, 0, 0);
}

__device__ __forceinline__ u16 f2bf(float f) {  // RNE fp32 -> bf16
  u32 u = __builtin_bit_cast(u32, f);
  u += 0x7fffu + ((u >> 16) & 1u);
  return (u16)(u >> 16);
}
__device__ __forceinline__ float bf2f(u16 h) {
  u32 u = ((u32)h) << 16;
  return __builtin_bit_cast(float, u);
}
__device__ __forceinline__ u16 bf16u(float f) {  // via compiler cvt path
  __hip_bfloat16 h = __float2bfloat16(f);
  u16 u;
  __builtin_memcpy(&u, &h, 2);
  return u;
}
__device__ __forceinline__ float exp2_hw(float x) {  // raw v_exp_f32
  float r;
  asm("v_exp_f32 %0, %1" : "=v"(r) : "v"(x));
  return r;
}

static constexpr int Bb = 2, Ss = 2048, Hh = 16, Dd = 1024;
static constexpr int Mm = Bb * Ss;  // 4096
static constexpr int NT = Ss / 64;  // 32 k/q tiles

// ---------------------------------------------------------------------------
// 0) fp32 -> bf16 convert
// ---------------------------------------------------------------------------
__global__ __launch_bounds__(256) void cvt_f32_bf16(const float* __restrict__ in,
                                                    u16* __restrict__ out, int n4) {
  for (int i = blockIdx.x * blockDim.x + threadIdx.x; i < n4;
       i += gridDim.x * blockDim.x) {
    float4 v = ((const float4*)in)[i];
    ushort4 o;
    o.x = f2bf(v.x); o.y = f2bf(v.y); o.z = f2bf(v.z); o.w = f2bf(v.w);
    ((ushort4*)out)[i] = o;
  }
}

// ---------------------------------------------------------------------------
// 0b) RoPE cos/sin table
// ---------------------------------------------------------------------------
__global__ __launch_bounds__(256) void build_rope_table(float2* __restrict__ tab) {
  int i = blockIdx.x * blockDim.x + threadIdx.x;
  if (i >= Ss * 32) return;
  int s = i >> 5, j = i & 31;
  const float log2_theta_over_32 = 0.41524101186091903f;  // log2(10000)/32
  float inv = exp2f(-(float)j * log2_theta_over_32);
  float fr = (float)s * inv;
  float sn, cs;
  sincosf(fr, &sn, &cs);
  tab[i] = make_float2(cs, sn);
}

// ---------------------------------------------------------------------------
// 1) GEMM C[m,n] = sum_k A[m,k] * B[n,k]
//    128x128 tile, dbuf LDS, T2 swizzle, T4 counted-vmcnt depth-2 pipeline.
//    (R9, verified: SQ_LDS_BANK_CONFLICT = 0)
// ---------------------------------------------------------------------------
template <bool OUT_BF16>
__global__ __launch_bounds__(256) void gemm_bt_kernel(const u16* __restrict__ A,
                                                      const u16* __restrict__ Bm,
                                                      void* __restrict__ Cv,
                                                      int Mdim, int Ndim, int Kdim) {
  __shared__ __align__(16) u16 As[2][128 * 64];
  __shared__ __align__(16) u16 Bs[2][128 * 64];
  const int tid = threadIdx.x;
  const int lane = tid & 63, wid = tid >> 6;
  const int wr = wid >> 1, wc = wid & 1;
  const int lr = lane & 15, lg = lane >> 4;

  // XCD-aware swizzle (T1): nwg % 8 == 0 for both launches (768, 256)
  const int nwg = gridDim.x * gridDim.y;
  const int orig = blockIdx.y * gridDim.x + blockIdx.x;
  const int cpx = nwg >> 3;
  const int swz = (orig & 7) * cpx + (orig >> 3);
  const int bx = swz % gridDim.x, by = swz / gridDim.x;
  const int m0 = by * 128, n0 = bx * 128;

  f32x4 acc[4][4] = {};

  // T2 (rule #21): LDS dest linear; global SOURCE granule pre-swizzled so
  // LDS(row, c) = Global(row, c ^ (row&7)).  row&7 == lane>>3 here.
  const int rowA = lane >> 3;
  const int colu = ((lane & 7) ^ rowA) * 8;  // u16 offset of 16B granule

  auto stage = [&](int buf, int kt) {
#pragma unroll
    for (int i = 0; i < 4; i++) {
      int chunk = wid * 4 + i;  // wave-uniform
      const u16* ga = A + (size_t)(m0 + chunk * 8 + rowA) * Kdim + kt + colu;
      gload_lds16(ga, &As[buf][chunk * 512]);
      const u16* gb = Bm + (size_t)(n0 + chunk * 8 + rowA) * Kdim + kt + colu;
      gload_lds16(gb, &Bs[buf][chunk * 512]);
    }
  };

  const int niter = Kdim >> 6;  // requires Kdim >= 128 (here: 1024)

  // prologue: fill both buffers, wait only for buf0's 8 loads
  stage(0, 0);
  stage(1, 64);
  asm volatile("s_waitcnt vmcnt(8)" ::: "memory");
  __builtin_amdgcn_sched_barrier(0);
  __builtin_amdgcn_s_barrier();
  __builtin_amdgcn_sched_barrier(0);

  const int rsw = (lr & 7) * 8;  // T2 read-side XOR (u16 units)
  int cur = 0;
  for (int it = 0; it < niter; ++it) {
#pragma unroll
    for (int ks = 0; ks < 2; ks++) {
      frag_t a[4], b[4];
#pragma unroll
      for (int mt = 0; mt < 4; mt++)
        a[mt] = *(const frag_t*)&As[cur][(wr * 64 + mt * 16 + lr) * 64 +
                                         ((ks * 32 + lg * 8) ^ rsw)];
#pragma unroll
      for (int nt = 0; nt < 4; nt++)
        b[nt] = *(const frag_t*)&Bs[cur][(wc * 64 + nt * 16 + lr) * 64 +
                                         ((ks * 32 + lg * 8) ^ rsw)];
#pragma unroll
      for (int mt = 0; mt < 4; mt++)
#pragma unroll
        for (int nt = 0; nt < 4; nt++)
          acc[mt][nt] = mfma16(a[mt], b[nt], acc[mt][nt]);
    }

    if (it + 1 < niter) {
      __builtin_amdgcn_s_barrier();      // all waves done reading buf cur
      __builtin_amdgcn_sched_barrier(0);
      if (it + 2 < niter) {
        stage(cur, (it + 2) << 6);       // refill just-read buf; 16 in flight
        asm volatile("s_waitcnt vmcnt(8)" ::: "memory");  // oldest 8 = next buf
      } else {
        asm volatile("s_waitcnt vmcnt(0)" ::: "memory");  // tail drain
      }
      __builtin_amdgcn_sched_barrier(0);
      __builtin_amdgcn_s_barrier();      // cross-wave: next buf visible
      __builtin_amdgcn_sched_barrier(0);
      cur ^= 1;
    }
  }

#pragma unroll
  for (int mt = 0; mt < 4; mt++)
#pragma unroll
    for (int nt = 0; nt < 4; nt++)
#pragma unroll
      for (int r = 0; r < 4; r++) {
        size_t row = (size_t)(m0 + wr * 64 + mt * 16 + lg * 4 + r);
        size_t col = (size_t)(n0 + wc * 64 + nt * 16 + lr);
        if (OUT_BF16)
          ((u16*)Cv)[row * Ndim + col] = f2bf(acc[mt][nt][r]);
        else
          ((float*)Cv)[row * Ndim + col] = acc[mt][nt][r];
      }
}

// ---------------------------------------------------------------------------
// 2) RoPE + reshape. Q pre-scaled by 0.125*log2(e): scores in log2 units.
// ---------------------------------------------------------------------------
__global__ __launch_bounds__(256) void rope_kernel(const u16* __restrict__ qkv,
                                                   const float2* __restrict__ tab,
                                                   u16* __restrict__ q_r,
                                                   u16* __restrict__ k_r,
                                                   u16* __restrict__ vt) {
  const int bh = blockIdx.y, b = bh >> 4, h = bh & 15;
  const int s0 = blockIdx.x * 64;
  const int t = threadIdx.x;
  __shared__ __align__(16) u16 Vls[64 * 72];

  const int srow = t >> 2, c4 = t & 3;
  const int s = s0 + srow;
  const size_t rowbase = (size_t)(b * Ss + s) * 3072 + h * 64 + c4 * 16;

  u16 xq[16] __attribute__((aligned(16)));
  u16 xk[16] __attribute__((aligned(16)));
  u16 xv[16] __attribute__((aligned(16)));
  *(uint4*)&xq[0] = *(const uint4*)(qkv + rowbase);
  *(uint4*)&xq[8] = *(const uint4*)(qkv + rowbase + 8);
  *(uint4*)&xk[0] = *(const uint4*)(qkv + rowbase + 1024);
  *(uint4*)&xk[8] = *(const uint4*)(qkv + rowbase + 1024 + 8);
  *(uint4*)&xv[0] = *(const uint4*)(qkv + rowbase + 2048);
  *(uint4*)&xv[8] = *(const uint4*)(qkv + rowbase + 2048 + 8);

  u16 oq[16] __attribute__((aligned(16)));
  u16 ok[16] __attribute__((aligned(16)));
  const int j0 = c4 * 8;
  const float qscale = 0.125f * 1.4426950408889634f;  // 1/sqrt(64) * log2(e)
#pragma unroll
  for (int p = 0; p < 8; p++) {
    float2 cs = tab[s * 32 + j0 + p];
    float q1 = bf2f(xq[2 * p]), q2 = bf2f(xq[2 * p + 1]);
    float k1 = bf2f(xk[2 * p]), k2 = bf2f(xk[2 * p + 1]);
    oq[2 * p]     = f2bf((q1 * cs.x - q2 * cs.y) * qscale);
    oq[2 * p + 1] = f2bf((q1 * cs.y + q2 * cs.x) * qscale);
    ok[2 * p]     = f2bf(k1 * cs.x - k2 * cs.y);
    ok[2 * p + 1] = f2bf(k1 * cs.y + k2 * cs.x);
  }
  const size_t obase = ((size_t)bh * Ss + s) * 64 + c4 * 16;
  *(uint4*)(q_r + obase)     = *(uint4*)&oq[0];
  *(uint4*)(q_r + obase + 8) = *(uint4*)&oq[8];
  *(uint4*)(k_r + obase)     = *(uint4*)&ok[0];
  *(uint4*)(k_r + obase + 8) = *(uint4*)&ok[8];

  *(uint4*)&Vls[srow * 72 + c4 * 16]     = *(uint4*)&xv[0];
  *(uint4*)&Vls[srow * 72 + c4 * 16 + 8] = *(uint4*)&xv[8];
  __syncthreads();
  const int d = t >> 2, cq = t & 3;
  u16 ov[16] __attribute__((aligned(16)));
#pragma unroll
  for (int i = 0; i < 16; i++) ov[i] = Vls[(cq * 16 + i) * 72 + d];
  const size_t vbase = ((size_t)bh * 64 + d) * Ss + s0 + cq * 16;
  *(uint4*)(vt + vbase)     = *(uint4*)&ov[0];
  *(uint4*)(vt + vbase + 8) = *(uint4*)&ov[8];
}

// ---------------------------------------------------------------------------
// 3) Flash attention (causal). R7 structure: 8 waves/block (512 thr), waves
//    0-3 own q-tile qtA rows, 4-7 own qtB (paired -> balanced, K/V staged
//    once for both tiles). Swapped QK^T, no max tracking, double-buffered
//    K/V, 1 barrier/iter. NEW (R10-verified math): T2 XOR-swizzled stride-64
//    K/V/P LDS -> conflicts ~0. LDS 48KB.
// ---------------------------------------------------------------------------
__global__ __launch_bounds__(512, 4) void attn_kernel(const u16* __restrict__ q_r,
                                                      const u16* __restrict__ k_r,
                                                      const u16* __restrict__ vt,
                                                      u16* __restrict__ o) {
  const int pr = blockIdx.x;  // 0..15
  const int bh = blockIdx.y;
  const int b = bh >> 4, h = bh & 15;
  const int tid = threadIdx.x;
  const int lane = tid & 63, w = tid >> 6;
  const int ww = w & 3;
  const int lr = lane & 15, lg = lane >> 4;

  const int qt = (w < 4) ? pr : (NT - 1 - pr);  // this wave's q-tile
  const int qtB = NT - 1 - pr;                  // loop bound

  __shared__ __align__(16) u16 Ks[2][64 * 64];
  __shared__ __align__(16) u16 Vs[2][64 * 64];
  __shared__ __align__(16) u16 Ps[8][16 * 64];

  const size_t kvbase = (size_t)bh * Ss * 64;
  const size_t vtbase = (size_t)bh * 64 * Ss;
  u16* Pw = &Ps[w][0];
  const int qrow = ww * 16 + lr;
  const int sw = lr & 7;  // read-side row XOR key (frag rows = *+lr)

  // ---- Q fragments in registers (once) ----
  frag_t q0f, q1f;
  {
    const u16* qa = q_r + kvbase + (size_t)(qt * 64 + qrow) * 64 + lg * 8;
    q0f = *(const frag_t*)qa;
    q1f = *(const frag_t*)(qa + 32);
  }

  // staging: 512 threads, one 16B chunk per tensor; LDS granule swizzled
  const int srow = tid >> 3, sgr = tid & 7;
  const int scolg = sgr * 8;                     // global col (u16)
  const int scols = (sgr ^ (srow & 7)) * 8;      // swizzled LDS col (u16)
  uint4 kreg, vreg;
  const u16* kp = k_r + kvbase;
  const u16* vp = vt + vtbase;

  auto issue = [&](int kt) {
    kreg = *(const uint4*)(kp + (size_t)(kt * 64 + srow) * 64 + scolg);
    vreg = *(const uint4*)(vp + (size_t)srow * Ss + kt * 64 + scolg);
  };
  auto commit = [&](int buf) {
    *(uint4*)&Ks[buf][srow * 64 + scols] = kreg;
    *(uint4*)&Vs[buf][srow * 64 + scols] = vreg;
  };

  f32x4 oacc[4] = {};
  float l_run = 0.f;

  issue(0);
  commit(0);
  __syncthreads();

  for (int kt = 0; kt <= qtB; kt++) {
    const int cur = kt & 1;
    const bool last = (kt == qtB);
    if (!last) issue(kt + 1);  // next tile's loads in flight under compute

    if (kt <= qt) {  // wave-uniform
      // ---- S^T = K @ Q^T (swizzled K reads) ----
      f32x4 sa[4];
      __builtin_amdgcn_s_setprio(1);
#pragma unroll
      for (int kf = 0; kf < 4; kf++) {
        frag_t k0 = *(const frag_t*)&Ks[cur][(kf * 16 + lr) * 64 + ((lg ^ sw) * 8)];
        frag_t k1 = *(const frag_t*)&Ks[cur][(kf * 16 + lr) * 64 + (((4 + lg) ^ sw) * 8)];
        sa[kf] = mfma16(k0, q0f, f32x4{0.f, 0.f, 0.f, 0.f});
        sa[kf] = mfma16(k1, q1f, sa[kf]);
      }
      __builtin_amdgcn_s_setprio(0);

      if (kt == qt) {  // diagonal mask (uniform branch)
#pragma unroll
        for (int kf = 0; kf < 4; kf++)
#pragma unroll
          for (int r = 0; r < 4; r++)
            if (kf * 16 + lg * 4 + r > qrow) sa[kf][r] = -1e30f;
      }

      // ---- p = exp2(s), lane-local l, pack, write P (swizzled b64) ----
      float ls = 0.f;
#pragma unroll
      for (int kf = 0; kf < 4; kf++) {
        float p0 = exp2_hw(sa[kf][0]), p1 = exp2_hw(sa[kf][1]);
        float p2 = exp2_hw(sa[kf][2]), p3 = exp2_hw(sa[kf][3]);
        ls += (p0 + p1) + (p2 + p3);
        ushort4 w4;
        w4.x = bf16u(p0); w4.y = bf16u(p1); w4.z = bf16u(p2); w4.w = bf16u(p3);
        // k-range [kf*16+lg*4, +4) -> granule kf*2+(lg>>1), half lg&1
        const int pg = (kf * 2 + (lg >> 1)) ^ sw;
        *(ushort4*)&Pw[lr * 64 + pg * 8 + (lg & 1) * 4] = w4;
      }
      l_run += ls;

      // ---- PV from LDS P (swizzled reads) ----
      __builtin_amdgcn_s_setprio(1);
#pragma unroll
      for (int ks = 0; ks < 2; ks++) {
        frag_t pa = *(const frag_t*)&Pw[lr * 64 + (((ks * 4 + lg) ^ sw) * 8)];
#pragma unroll
        for (int df = 0; df < 4; df++) {
          frag_t bv = *(const frag_t*)&Vs[cur][(df * 16 + lr) * 64 +
                                               (((ks * 4 + lg) ^ sw) * 8)];
          oacc[df] = mfma16(pa, bv, oacc[df]);
        }
      }
      __builtin_amdgcn_s_setprio(0);
    }

    if (!last) commit(cur ^ 1);
    __syncthreads();
  }

  // ---- epilogue: reduce l across lg groups, O /= l, write bf16 ----
  l_run += __shfl_xor(l_run, 16);
  l_run += __shfl_xor(l_run, 32);
#pragma unroll
  for (int r = 0; r < 4; r++) {
    float il = 1.0f / __shfl(l_run, lg * 4 + r);
    size_t row = (size_t)b * Ss + qt * 64 + ww * 16 + lg * 4 + r;
#pragma unroll
    for (int df = 0; df < 4; df++)
      o[row * 1024 + h * 64 + df * 16 + lr] = f2bf(oacc[df][r] * il);
  }
}

// ---------------------------------------------------------------------------
// launch
// ---------------------------------------------------------------------------
extern "C" void kernel_launch(void* const* d_in, const int* in_sizes, int n_in,
                              void* d_out, int out_size, void* d_ws, size_t ws_size,
                              hipStream_t stream) {
  const float* x    = (const float*)d_in[0];
  const float* Wqkv = (const float*)d_in[1];
  const float* Wo   = (const float*)d_in[2];
  float* out = (float*)d_out;
  char* ws = (char*)d_ws;

  constexpr size_t TAB_OFF  = 0;                       // 512KB
  constexpr size_t XB_OFF   = TAB_OFF + 524288;        // 8MB
  constexpr size_t WQB_OFF  = XB_OFF + 8388608;        // 6MB
  constexpr size_t WOB_OFF  = WQB_OFF + 6291456;       // 2MB
  constexpr size_t QKV_OFF  = WOB_OFF + 2097152;       // 24MB
  constexpr size_t QR_OFF   = QKV_OFF + 25165824;      // 8MB
  constexpr size_t KR_OFF   = QR_OFF + 8388608;        // 8MB
  constexpr size_t VT_OFF   = KR_OFF + 8388608;        // 8MB
  constexpr size_t AO_OFF   = VT_OFF + 8388608;        // 8MB

  float2* tab = (float2*)(ws + TAB_OFF);
  u16* xb     = (u16*)(ws + XB_OFF);
  u16* wqkvb  = (u16*)(ws + WQB_OFF);
  u16* wob    = (u16*)(ws + WOB_OFF);
  u16* qkv    = (u16*)(ws + QKV_OFF);
  u16* q_r    = (u16*)(ws + QR_OFF);
  u16* k_r    = (u16*)(ws + KR_OFF);
  u16* vt     = (u16*)(ws + VT_OFF);
  u16* ao     = (u16*)(ws + AO_OFF);

  build_rope_table<<<256, 256, 0, stream>>>(tab);
  cvt_f32_bf16<<<2048, 256, 0, stream>>>(x, xb, Mm * Dd / 4);
  cvt_f32_bf16<<<1536, 256, 0, stream>>>(Wqkv, wqkvb, 3 * Dd * Dd / 4);
  cvt_f32_bf16<<<512, 256, 0, stream>>>(Wo, wob, Dd * Dd / 4);

  gemm_bt_kernel<true><<<dim3(3 * Dd / 128, Mm / 128), 256, 0, stream>>>(
      xb, wqkvb, qkv, Mm, 3 * Dd, Dd);

  rope_kernel<<<dim3(Ss / 64, Bb * Hh), 256, 0, stream>>>(qkv, tab, q_r, k_r, vt);

  attn_kernel<<<dim3(NT / 2, Bb * Hh), 512, 0, stream>>>(q_r, k_r, vt, ao);

  gemm_bt_kernel<false><<<dim3(Dd / 128, Mm / 128), 256, 0, stream>>>(
      ao, wob, out, Mm, Dd, Dd);
}